// Round 5
// baseline (168.864 us; speedup 1.0000x reference)
//
#include <hip/hip_runtime.h>

#define BATCH 256
#define SEQ 2048
#define NT 48
#define START_TAG 46
#define END_TAG 47
#define LN2f  0.6931471805599453f
#define LOG2E 1.4426950408889634f

// ws layout
#define TAF 0          // A-frags of exp(trans) bf16: [9][64] x 8B   (4608 B)
#define TBF 4608       // B-frag exp(trans) f32:      [9][64] x 16B  (9216 B)
#define TSC 16384      // per-chunk log2 scales: [B][NCH] f32        (<=64 KiB)
#define TW  131072     // chunk matrices M^T bf16: [B][NCH][48][48]

typedef float v2f __attribute__((ext_vector_type(2)));
typedef float v4f __attribute__((ext_vector_type(4)));
typedef short s16x4 __attribute__((ext_vector_type(4)));
typedef unsigned int u32;
typedef u32 u32x2 __attribute__((ext_vector_type(2)));
typedef u32 u32x4 __attribute__((ext_vector_type(4)));

__device__ __forceinline__ u32 pkbf(float a, float b) {
    u32 r;
    asm("v_cvt_pk_bf16_f32 %0, %1, %2" : "=v"(r) : "v"(a), "v"(b));
    return r;
}

__device__ __forceinline__ float rfl(float x) {
    return __builtin_bit_cast(float,
        __builtin_amdgcn_readfirstlane(__builtin_bit_cast(int, x)));
}

#if defined(__has_builtin)
#if __has_builtin(__builtin_amdgcn_mfma_f32_16x16x16bf16_1k)
#define MFMA1K 1
#endif
#endif

__device__ __forceinline__ v4f mfma16(s16x4 a, s16x4 b, v4f c) {
#ifdef MFMA1K
    return __builtin_amdgcn_mfma_f32_16x16x16bf16_1k(a, b, c, 0, 0, 0);
#else
    v4f d;
    asm volatile("v_mfma_f32_16x16x16_bf16 %0, %1, %2, %3\n\ts_nop 7\n\ts_nop 7"
                 : "=v"(d) : "v"(a), "v"(b), "v"(c));
    return d;
#endif
}

// ---------------------------------------------------------------------------
// Kernel 0: build exp(trans) fragments once. 1 block x 64.
// A-frag (tile I,K): lane holds E[I*16+(l&15)][K*16+(l>>4)*4+i], i=0..3, bf16.
// B-frag (tile K,J): lane holds E[K*16+(l>>4)*4+i][J*16+(l&15)], f32.
// ---------------------------------------------------------------------------
__global__ void __launch_bounds__(64)
crf_setup(const float* __restrict__ trans, void* ws) {
    __shared__ float el[NT * NT];
    const int lane = threadIdx.x, ln = lane & 15, g = lane >> 4;
    #pragma unroll
    for (int m = 0; m < 36; ++m) {
        int idx = lane + 64 * m;
        el[idx] = __expf(trans[idx]);
    }
    u32x2* AF = (u32x2*)((char*)ws + TAF);
    v4f*   BF = (v4f*)((char*)ws + TBF);
    #pragma unroll
    for (int I = 0; I < 3; ++I)
        #pragma unroll
        for (int K = 0; K < 3; ++K) {
            const v4f ev = *(const v4f*)&el[(I * 16 + ln) * NT + K * 16 + g * 4];
            u32x2 w;
            w.x = pkbf(ev.x, ev.y);
            w.y = pkbf(ev.z, ev.w);
            AF[(I * 3 + K) * 64 + lane] = w;
        }
    #pragma unroll
    for (int K = 0; K < 3; ++K)
        #pragma unroll
        for (int J = 0; J < 3; ++J) {
            v4f v;
            #pragma unroll
            for (int i = 0; i < 4; ++i)
                v[i] = el[(K * 16 + g * 4 + i) * NT + J * 16 + ln];
            BF[(K * 3 + J) * 64 + lane] = v;
        }
}

// ---------------------------------------------------------------------------
// Kernel 1: 4 independent chunk-waves per 256-thread WG (no barriers, no LDS)
// Per (b, chunk c): M_c = prod_{t in chunk} (D_t E) via MFMA chain, M kept in
// B-frag(==C) layout.  Per step: sp = exp2(f*log2e - lg) (rescale folded into
// exponent, lg = log2 of previous step's raw P00); 27 MFMA; scale+cvt_pk.
// Emissions loaded directly from global (lane-group-uniform v4f -> broadcast),
// software-pipelined one step ahead.
// ---------------------------------------------------------------------------
template<int LCH_, int NCH_>
__global__ void __launch_bounds__(256, 4)
crf_phase1(const float* __restrict__ feat, const int* __restrict__ seqlen,
           void* __restrict__ ws) {
    const int b = blockIdx.x;
    const int wid = threadIdx.x >> 6;
    const int c = blockIdx.y * 4 + wid;
    const int t0 = c * LCH_;
    const int L = seqlen[b];
    int n = L - t0;
    if (n <= 0) return;
    if (n > LCH_) n = LCH_;

    const int lane = threadIdx.x & 63, ln = lane & 15, g = lane >> 4;

    const u32x2* AF = (const u32x2*)((const char*)ws + TAF);
    const v4f*   BF = (const v4f*)((const char*)ws + TBF);

    s16x4 aw[3][3];
    #pragma unroll
    for (int I = 0; I < 3; ++I)
        #pragma unroll
        for (int K = 0; K < 3; ++K)
            aw[I][K] = __builtin_bit_cast(s16x4, AF[(I * 3 + K) * 64 + lane]);

    // lane-group base: this lane's 4 emission rows start at +g*4
    const float* fb0 = feat + ((size_t)b * SEQ + t0) * NT + g * 4;

    // --- init M = D_{t0} E  (row k scaled by exp(emit_{t0}[k]))
    s16x4 mw[3][3];
    {
        v4f emx[3];
        #pragma unroll
        for (int K = 0; K < 3; ++K) {
            v4f f = *(const v4f*)(fb0 + K * 16);
            #pragma unroll
            for (int i = 0; i < 4; ++i)
                emx[K][i] = __builtin_amdgcn_exp2f(f[i] * LOG2E);
        }
        #pragma unroll
        for (int K = 0; K < 3; ++K)
            #pragma unroll
            for (int J = 0; J < 3; ++J) {
                v4f sc = BF[(K * 3 + J) * 64 + lane] * emx[K];
                mw[K][J] = __builtin_bit_cast(s16x4,
                    (u32x2){pkbf(sc.x, sc.y), pkbf(sc.z, sc.w)});
            }
    }

    // --- prefetch row 1, pre-scaled by log2e
    v4f ef[3];
    #pragma unroll
    for (int K = 0; K < 3; ++K)
        ef[K] = *(const v4f*)(fb0 + NT + K * 16) * LOG2E;

    float Lc = 0.f, lg = 0.f;
    const v4f kz = {0.f, 0.f, 0.f, 0.f};

    for (int t = 1; t < n; ++t) {
        // sp = exp2(f*log2e - lg) = exp(f) / gn_prev   (lagged rescale)
        v4f sp[3];
        #pragma unroll
        for (int K = 0; K < 3; ++K) {
            v4f e = ef[K] - lg;
            #pragma unroll
            for (int i = 0; i < 4; ++i) sp[K][i] = __builtin_amdgcn_exp2f(e[i]);
        }
        Lc += lg;

        // issue next row's loads (uniform-per-wave row index; clamp last)
        int rr = t + 1;
        if (t0 + rr == SEQ) rr = 0;
        const float* fr = fb0 + (size_t)rr * NT;
        v4f fv0 = *(const v4f*)(fr);
        v4f fv1 = *(const v4f*)(fr + 16);
        v4f fv2 = *(const v4f*)(fr + 32);

        v4f acc[3][3];
        #pragma unroll
        for (int I = 0; I < 3; ++I)
            #pragma unroll
            for (int J = 0; J < 3; ++J) {
                v4f a = mfma16(aw[I][0], mw[0][J], kz);
                a     = mfma16(aw[I][1], mw[1][J], a);
                acc[I][J] = mfma16(aw[I][2], mw[2][J], a);
            }

        const float gn = rfl(acc[0][0].x);   // raw P00 -> next-step scale
        #pragma unroll
        for (int K = 0; K < 3; ++K)
            #pragma unroll
            for (int J = 0; J < 3; ++J) {
                v4f sc = acc[K][J] * sp[K];  // v_pk_mul_f32 x2
                mw[K][J] = __builtin_bit_cast(s16x4,
                    (u32x2){pkbf(sc.x, sc.y), pkbf(sc.z, sc.w)});
            }
        lg = __log2f(gn);
        ef[0] = fv0 * LOG2E;
        ef[1] = fv1 * LOG2E;
        ef[2] = fv2 * LOG2E;
    }

    // store M^T bf16 (element M[kk][nn] -> byte 2*(nn*48+kk)) + scale
    char* wb = (char*)ws + TW + ((size_t)(b * NCH_ + c)) * 4608;
    #pragma unroll
    for (int K = 0; K < 3; ++K)
        #pragma unroll
        for (int J = 0; J < 3; ++J) {
            u32x2 w = __builtin_bit_cast(u32x2, mw[K][J]);
            *(u32*)(wb + 2 * ((J * 16 + ln) * NT + K * 16 + g * 4))     = w.x;
            *(u32*)(wb + 2 * ((J * 16 + ln) * NT + K * 16 + g * 4 + 2)) = w.y;
        }
    if (lane == 0)
        ((float*)((char*)ws + TSC))[b * NCH_ + c] = Lc;
}

// ---------------------------------------------------------------------------
// Kernel 2: per sample, u^T <- u^T * M_c for c = nb-1..0; lane j owns u[j];
// M^T row j contiguous bf16; next chunk's row double-buffered.
// ---------------------------------------------------------------------------
template<int LCH_, int NCH_>
__global__ void __launch_bounds__(64)
crf_phase2(const float* __restrict__ trans, const int* __restrict__ seqlen,
           const void* __restrict__ ws, float* __restrict__ out) {
    const int b = blockIdx.x;
    const int lane = threadIdx.x;
    const int j = (lane < NT) ? lane : (lane - 16);
    __shared__ v4f hs4[12];
    float* hs = (float*)hs4;

    const int L = seqlen[b];
    const int nb = (L + LCH_ - 1) / LCH_;
    const float* sc = (const float*)((const char*)ws + TSC) + b * NCH_;
    const char* wbase = (const char*)ws + TW + (size_t)b * NCH_ * 4608;

    float q = __expf(trans[END_TAG * NT + j]);   // u0 (exp(MIN)=0 -> col END)
    float D = 0.f;

    u32x4 buf[6];
    {
        const u32x4* wr = (const u32x4*)(wbase + (size_t)(nb - 1) * 4608 + j * 96);
        #pragma unroll
        for (int m = 0; m < 6; ++m) buf[m] = wr[m];
    }

    for (int c = nb - 1; c >= 0; --c) {
        u32x4 cur[6];
        #pragma unroll
        for (int m = 0; m < 6; ++m) cur[m] = buf[m];
        if (c > 0) {
            const u32x4* wr = (const u32x4*)(wbase + (size_t)(c - 1) * 4608 + j * 96);
            #pragma unroll
            for (int m = 0; m < 6; ++m) buf[m] = wr[m];
        }

        if (lane < NT) hs[lane] = q;
        v4f hq[12];
        #pragma unroll
        for (int k = 0; k < 12; ++k) hq[k] = hs4[k];
        const float h0 = hq[0][0];

        v2f a = {0.f, 0.f};
        #pragma unroll
        for (int m = 0; m < 6; ++m) {
            #pragma unroll
            for (int p = 0; p < 4; ++p) {
                const int i = 2 * (4 * m + p);
                u32 w = cur[m][p];
                v2f wp;
                wp.x = __builtin_bit_cast(float, w << 16);
                wp.y = __builtin_bit_cast(float, w & 0xffff0000u);
                v2f up = { hq[i >> 2][i & 3], hq[i >> 2][(i & 3) + 1] };
                a += wp * up;
            }
        }
        const float dot = a.x + a.y;
        q = dot * __builtin_amdgcn_rcpf(h0);
        D += __log2f(h0) + sc[c];
    }
    if (lane < NT) hs[lane] = q;
    if (lane == 0)
        out[b] = LN2f * (D + __log2f(hs[START_TAG]));
}

// ---------------------------------------------------------------------------
// Fallback: proven round-2 scalar kernel (ws too small)
// ---------------------------------------------------------------------------
__global__ void __launch_bounds__(64)
crf_scalar(const float* __restrict__ features, const float* __restrict__ transitions,
           const int* __restrict__ seq_len, float* __restrict__ out) {
    const int b = blockIdx.x;
    const int lane = threadIdx.x;
    const int j = (lane < NT) ? lane : (lane - 16);
    __shared__ v4f hs4[NT / 4];
    float* hs = (float*)hs4;

    v2f E2[NT / 2];
    {
        const v4f* trow = (const v4f*)(transitions + j * NT);
        #pragma unroll
        for (int k = 0; k < NT / 4; ++k) {
            v4f tv = trow[k];
            E2[2 * k].x = __expf(tv.x); E2[2 * k].y = __expf(tv.y);
            E2[2 * k + 1].x = __expf(tv.z); E2[2 * k + 1].y = __expf(tv.w);
        }
    }
    const float Eend = __expf(transitions[END_TAG * NT + j]);
    const int L = seq_len[b];
    const float* fbase = features + ((size_t)b * SEQ) * NT + j;

    float q = E2[START_TAG / 2].x * __expf(fbase[0]);
    float Clog2 = 0.0f;
    if (lane < NT) hs[lane] = q;

    float fb[8];
    #pragma unroll
    for (int u = 0; u < 8; ++u) {
        int tp = 1 + u;
        fb[u] = fbase[(size_t)(tp < SEQ ? tp : 0) * NT];
    }

    auto STEP = [&](float femit) {
        v4f hq[NT / 4];
        #pragma unroll
        for (int k = 0; k < NT / 4; ++k) hq[k] = hs4[k];
        float h0 = hq[0].x;
        float r = __builtin_amdgcn_rcpf(h0);
        float e = __expf(femit);
        float re = r * e;
        v2f a0 = {0.f, 0.f}, a1 = {0.f, 0.f};
        #pragma unroll
        for (int k = 0; k < NT / 4; ++k) {
            v2f lo = { hq[k].x, hq[k].y };
            v2f hi = { hq[k].z, hq[k].w };
            a0 += E2[2 * k] * lo;
            a1 += E2[2 * k + 1] * hi;
        }
        float d = (a0.x + a1.x) + (a0.y + a1.y);
        q = d * re;
        Clog2 += __log2f(h0);
        if (lane < NT) hs[lane] = q;
    };

    int t = 1;
    while (t + 8 <= L) {
        #pragma unroll
        for (int u = 0; u < 8; ++u) {
            STEP(fb[u]);
            int tp = t + u + 8;
            fb[u] = fbase[(size_t)(tp < SEQ ? tp : 0) * NT];
        }
        t += 8;
    }
    #pragma unroll
    for (int u = 0; u < 8; ++u)
        if (t + u < L) STEP(fb[u]);

    float term = (lane < NT) ? q * Eend : 0.0f;
    #pragma unroll
    for (int m = 32; m >= 1; m >>= 1) term += __shfl_xor(term, m, 64);
    if (lane == 0) out[b] = LN2f * (Clog2 + __log2f(term));
}

extern "C" void kernel_launch(void* const* d_in, const int* in_sizes, int n_in,
                              void* d_out, int out_size, void* d_ws, size_t ws_size,
                              hipStream_t stream) {
    const float* features    = (const float*)d_in[0];
    const float* transitions = (const float*)d_in[1];
    const int*   seqlen      = (const int*)d_in[2];
    float* out = (float*)d_out;

    const size_t need64 = (size_t)TW + (size_t)BATCH * 64 * 4608;   // ~75.6 MB
    const size_t need32 = (size_t)TW + (size_t)BATCH * 32 * 4608;   // ~37.9 MB
    if (ws_size >= need64) {
        crf_setup<<<1, 64, 0, stream>>>(transitions, d_ws);
        crf_phase1<32, 64><<<dim3(BATCH, 16), 256, 0, stream>>>(features, seqlen, d_ws);
        crf_phase2<32, 64><<<BATCH, 64, 0, stream>>>(transitions, seqlen, d_ws, out);
    } else if (ws_size >= need32) {
        crf_setup<<<1, 64, 0, stream>>>(transitions, d_ws);
        crf_phase1<64, 32><<<dim3(BATCH, 8), 256, 0, stream>>>(features, seqlen, d_ws);
        crf_phase2<64, 32><<<BATCH, 64, 0, stream>>>(transitions, seqlen, d_ws, out);
    } else {
        crf_scalar<<<BATCH, 64, 0, stream>>>(features, transitions, seqlen, out);
    }
}

// Round 6
// 162.435 us; speedup vs baseline: 1.0396x; 1.0396x over previous
//
#include <hip/hip_runtime.h>

#define BATCH 256
#define SEQ 2048
#define NT 48
#define START_TAG 46
#define END_TAG 47
#define LN2f  0.6931471805599453f
#define LOG2E 1.4426950408889634f

// ws layout
#define TAF 0          // A-frags of exp(trans) bf16: [9][64] x 8B   (4608 B)
#define TBF 4608       // B-frag exp(trans) f32:      [9][64] x 16B  (9216 B)
#define TSC 16384      // per-chunk log2 scales: [B][NCH] f32        (<=64 KiB)
#define TW  131072     // chunk matrices M^T bf16: [B][NCH][48][48]

typedef float v2f __attribute__((ext_vector_type(2)));
typedef float v4f __attribute__((ext_vector_type(4)));
typedef short s16x4 __attribute__((ext_vector_type(4)));
typedef unsigned int u32;
typedef u32 u32x2 __attribute__((ext_vector_type(2)));
typedef u32 u32x4 __attribute__((ext_vector_type(4)));

__device__ __forceinline__ u32 pkbf(float a, float b) {
    u32 r;
    asm("v_cvt_pk_bf16_f32 %0, %1, %2" : "=v"(r) : "v"(a), "v"(b));
    return r;
}

__device__ __forceinline__ float rfl(float x) {
    return __builtin_bit_cast(float,
        __builtin_amdgcn_readfirstlane(__builtin_bit_cast(int, x)));
}

#if defined(__has_builtin)
#if __has_builtin(__builtin_amdgcn_mfma_f32_16x16x16bf16_1k)
#define MFMA1K 1
#endif
#endif

__device__ __forceinline__ v4f mfma16(s16x4 a, s16x4 b, v4f c) {
#ifdef MFMA1K
    return __builtin_amdgcn_mfma_f32_16x16x16bf16_1k(a, b, c, 0, 0, 0);
#else
    v4f d;
    asm volatile("v_mfma_f32_16x16x16_bf16 %0, %1, %2, %3\n\ts_nop 7\n\ts_nop 7"
                 : "=v"(d) : "v"(a), "v"(b), "v"(c));
    return d;
#endif
}

// ---------------------------------------------------------------------------
// Kernel 0: build exp(trans) fragments once. 1 block x 64.
// A-frag (tile I,K): lane holds E[I*16+(l&15)][K*16+(l>>4)*4+i], i=0..3, bf16.
// B-frag (tile K,J): lane holds E[K*16+(l>>4)*4+i][J*16+(l&15)], f32.
// ---------------------------------------------------------------------------
__global__ void __launch_bounds__(64)
crf_setup(const float* __restrict__ trans, void* ws) {
    __shared__ float el[NT * NT];
    const int lane = threadIdx.x, ln = lane & 15, g = lane >> 4;
    #pragma unroll
    for (int m = 0; m < 36; ++m) {
        int idx = lane + 64 * m;
        el[idx] = __expf(trans[idx]);
    }
    u32x2* AF = (u32x2*)((char*)ws + TAF);
    v4f*   BF = (v4f*)((char*)ws + TBF);
    #pragma unroll
    for (int I = 0; I < 3; ++I)
        #pragma unroll
        for (int K = 0; K < 3; ++K) {
            const v4f ev = *(const v4f*)&el[(I * 16 + ln) * NT + K * 16 + g * 4];
            u32x2 w;
            w.x = pkbf(ev.x, ev.y);
            w.y = pkbf(ev.z, ev.w);
            AF[(I * 3 + K) * 64 + lane] = w;
        }
    #pragma unroll
    for (int K = 0; K < 3; ++K)
        #pragma unroll
        for (int J = 0; J < 3; ++J) {
            v4f v;
            #pragma unroll
            for (int i = 0; i < 4; ++i)
                v[i] = el[(K * 16 + g * 4 + i) * NT + J * 16 + ln];
            BF[(K * 3 + J) * 64 + lane] = v;
        }
}

// ---------------------------------------------------------------------------
// Kernel 1: 4 independent chunk-waves per 256-thread WG (no barriers; each
// wave owns a private LDS slice, wave-ordered DS ops).
// Per (b, chunk c): M_c = prod_{t in chunk} (D_t E) via MFMA chain, M kept in
// B-frag(==C) layout.  Per step: sp = exp2(f*log2e - lg) (lagged P00 rescale
// folded into exponent); 27 MFMA ordered K-OUTER so the 9 (I,J) chains are
// independent between dependency levels (round-5 K-inner order let the
// compiler serialize them at 48 VGPRs -> ~500 cyc/step latency exposure);
// then row-scale + cvt_pk -> bf16.
// Emissions: whole chunk staged to LDS up front (6 KB/wave), per-step
// ds_read_b128 broadcast prefetched one step ahead.
// ---------------------------------------------------------------------------
template<int LCH_, int NCH_>
__global__ void __launch_bounds__(256, 3)
crf_phase1(const float* __restrict__ feat, const int* __restrict__ seqlen,
           void* __restrict__ ws) {
    const int b = blockIdx.x;
    const int wid = threadIdx.x >> 6;
    const int c = blockIdx.y * 4 + wid;
    const int t0 = c * LCH_;
    const int L = seqlen[b];
    int n = L - t0;
    if (n <= 0) return;
    if (n > LCH_) n = LCH_;

    const int lane = threadIdx.x & 63, ln = lane & 15, g = lane >> 4;

    // per-wave emission slice (+16 pad: t+1 prefetch at t=n-1 may touch it)
    __shared__ v4f flv[4][LCH_ * 12 + 16];
    v4f* fl = flv[wid];

    const u32x2* AF = (const u32x2*)((const char*)ws + TAF);
    const v4f*   BF = (const v4f*)((const char*)ws + TBF);

    s16x4 aw[3][3];
    #pragma unroll
    for (int I = 0; I < 3; ++I)
        #pragma unroll
        for (int K = 0; K < 3; ++K)
            aw[I][K] = __builtin_bit_cast(s16x4, AF[(I * 3 + K) * 64 + lane]);

    // stage the whole chunk's emissions (chunk is always within SEQ rows)
    {
        constexpr int NLD = (LCH_ * 12) / 64;
        const v4f* fg = (const v4f*)(feat + ((size_t)b * SEQ + t0) * NT);
        v4f st[NLD];
        #pragma unroll
        for (int m = 0; m < NLD; ++m) st[m] = fg[m * 64 + lane];
        #pragma unroll
        for (int m = 0; m < NLD; ++m) fl[m * 64 + lane] = st[m];
    }

    // init M = D_{t0} E  (row k scaled by exp(emit_{t0}[k]))
    s16x4 mw[3][3];
    {
        v4f emx[3];
        #pragma unroll
        for (int K = 0; K < 3; ++K) {
            v4f f = fl[K * 4 + g];
            #pragma unroll
            for (int i = 0; i < 4; ++i)
                emx[K][i] = __builtin_amdgcn_exp2f(f[i] * LOG2E);
        }
        #pragma unroll
        for (int K = 0; K < 3; ++K)
            #pragma unroll
            for (int J = 0; J < 3; ++J) {
                v4f sc = BF[(K * 3 + J) * 64 + lane] * emx[K];
                mw[K][J] = __builtin_bit_cast(s16x4,
                    (u32x2){pkbf(sc.x, sc.y), pkbf(sc.z, sc.w)});
            }
    }

    // prefetch row 1, pre-scaled by log2e
    v4f ef[3];
    #pragma unroll
    for (int K = 0; K < 3; ++K)
        ef[K] = fl[12 + K * 4 + g] * LOG2E;

    float Lc = 0.f, lg = 0.f;
    const v4f kz = {0.f, 0.f, 0.f, 0.f};

    for (int t = 1; t < n; ++t) {
        // sp = exp2(f*log2e - lg) = exp(f) / gn_prev   (lagged rescale)
        v4f sp[3];
        #pragma unroll
        for (int K = 0; K < 3; ++K) {
            v4f e = ef[K] - lg;
            #pragma unroll
            for (int i = 0; i < 4; ++i) sp[K][i] = __builtin_amdgcn_exp2f(e[i]);
        }
        Lc += lg;

        // prefetch next row's emissions (broadcast ds_read_b128)
        const int tb = (t + 1) * 12 + g;
        v4f fv0 = fl[tb];
        v4f fv1 = fl[tb + 4];
        v4f fv2 = fl[tb + 8];

        // MFMA, K-outer: 9 independent MFMAs per dependency level
        v4f acc[3][3];
        #pragma unroll
        for (int K = 0; K < 3; ++K)
            #pragma unroll
            for (int I = 0; I < 3; ++I)
                #pragma unroll
                for (int J = 0; J < 3; ++J)
                    acc[I][J] = mfma16(aw[I][K], mw[K][J],
                                       K == 0 ? kz : acc[I][J]);

        const float gn = rfl(acc[0][0].x);   // raw P00 -> next-step scale
        #pragma unroll
        for (int K = 0; K < 3; ++K)
            #pragma unroll
            for (int J = 0; J < 3; ++J) {
                v4f sc = acc[K][J] * sp[K];  // v_pk_mul_f32 x2
                mw[K][J] = __builtin_bit_cast(s16x4,
                    (u32x2){pkbf(sc.x, sc.y), pkbf(sc.z, sc.w)});
            }
        lg = __log2f(gn);
        ef[0] = fv0 * LOG2E;
        ef[1] = fv1 * LOG2E;
        ef[2] = fv2 * LOG2E;
    }

    // store M^T bf16 (element M[kk][nn] -> byte 2*(nn*48+kk)) + scale
    char* wb = (char*)ws + TW + ((size_t)(b * NCH_ + c)) * 4608;
    #pragma unroll
    for (int K = 0; K < 3; ++K)
        #pragma unroll
        for (int J = 0; J < 3; ++J) {
            u32x2 w = __builtin_bit_cast(u32x2, mw[K][J]);
            *(u32*)(wb + 2 * ((J * 16 + ln) * NT + K * 16 + g * 4))     = w.x;
            *(u32*)(wb + 2 * ((J * 16 + ln) * NT + K * 16 + g * 4 + 2)) = w.y;
        }
    if (lane == 0)
        ((float*)((char*)ws + TSC))[b * NCH_ + c] = Lc;
}

// ---------------------------------------------------------------------------
// Kernel 2: per sample, u^T <- u^T * M_c for c = nb-1..0; lane j owns u[j];
// M^T row j contiguous bf16; next chunk's row double-buffered.
// ---------------------------------------------------------------------------
template<int LCH_, int NCH_>
__global__ void __launch_bounds__(64)
crf_phase2(const float* __restrict__ trans, const int* __restrict__ seqlen,
           const void* __restrict__ ws, float* __restrict__ out) {
    const int b = blockIdx.x;
    const int lane = threadIdx.x;
    const int j = (lane < NT) ? lane : (lane - 16);
    __shared__ v4f hs4[12];
    float* hs = (float*)hs4;

    const int L = seqlen[b];
    const int nb = (L + LCH_ - 1) / LCH_;
    const float* sc = (const float*)((const char*)ws + TSC) + b * NCH_;
    const char* wbase = (const char*)ws + TW + (size_t)b * NCH_ * 4608;

    float q = __expf(trans[END_TAG * NT + j]);   // u0 (exp(MIN)=0 -> col END)
    float D = 0.f;

    u32x4 buf[6];
    {
        const u32x4* wr = (const u32x4*)(wbase + (size_t)(nb - 1) * 4608 + j * 96);
        #pragma unroll
        for (int m = 0; m < 6; ++m) buf[m] = wr[m];
    }

    for (int c = nb - 1; c >= 0; --c) {
        u32x4 cur[6];
        #pragma unroll
        for (int m = 0; m < 6; ++m) cur[m] = buf[m];
        if (c > 0) {
            const u32x4* wr = (const u32x4*)(wbase + (size_t)(c - 1) * 4608 + j * 96);
            #pragma unroll
            for (int m = 0; m < 6; ++m) buf[m] = wr[m];
        }

        if (lane < NT) hs[lane] = q;
        v4f hq[12];
        #pragma unroll
        for (int k = 0; k < 12; ++k) hq[k] = hs4[k];
        const float h0 = hq[0][0];

        v2f a = {0.f, 0.f};
        #pragma unroll
        for (int m = 0; m < 6; ++m) {
            #pragma unroll
            for (int p = 0; p < 4; ++p) {
                const int i = 2 * (4 * m + p);
                u32 w = cur[m][p];
                v2f wp;
                wp.x = __builtin_bit_cast(float, w << 16);
                wp.y = __builtin_bit_cast(float, w & 0xffff0000u);
                v2f up = { hq[i >> 2][i & 3], hq[i >> 2][(i & 3) + 1] };
                a += wp * up;
            }
        }
        const float dot = a.x + a.y;
        q = dot * __builtin_amdgcn_rcpf(h0);
        D += __log2f(h0) + sc[c];
    }
    if (lane < NT) hs[lane] = q;
    if (lane == 0)
        out[b] = LN2f * (D + __log2f(hs[START_TAG]));
}

// ---------------------------------------------------------------------------
// Fallback: proven round-2 scalar kernel (ws too small)
// ---------------------------------------------------------------------------
__global__ void __launch_bounds__(64)
crf_scalar(const float* __restrict__ features, const float* __restrict__ transitions,
           const int* __restrict__ seq_len, float* __restrict__ out) {
    const int b = blockIdx.x;
    const int lane = threadIdx.x;
    const int j = (lane < NT) ? lane : (lane - 16);
    __shared__ v4f hs4[NT / 4];
    float* hs = (float*)hs4;

    v2f E2[NT / 2];
    {
        const v4f* trow = (const v4f*)(transitions + j * NT);
        #pragma unroll
        for (int k = 0; k < NT / 4; ++k) {
            v4f tv = trow[k];
            E2[2 * k].x = __expf(tv.x); E2[2 * k].y = __expf(tv.y);
            E2[2 * k + 1].x = __expf(tv.z); E2[2 * k + 1].y = __expf(tv.w);
        }
    }
    const float Eend = __expf(transitions[END_TAG * NT + j]);
    const int L = seq_len[b];
    const float* fbase = features + ((size_t)b * SEQ) * NT + j;

    float q = E2[START_TAG / 2].x * __expf(fbase[0]);
    float Clog2 = 0.0f;
    if (lane < NT) hs[lane] = q;

    float fb[8];
    #pragma unroll
    for (int u = 0; u < 8; ++u) {
        int tp = 1 + u;
        fb[u] = fbase[(size_t)(tp < SEQ ? tp : 0) * NT];
    }

    auto STEP = [&](float femit) {
        v4f hq[NT / 4];
        #pragma unroll
        for (int k = 0; k < NT / 4; ++k) hq[k] = hs4[k];
        float h0 = hq[0].x;
        float r = __builtin_amdgcn_rcpf(h0);
        float e = __expf(femit);
        float re = r * e;
        v2f a0 = {0.f, 0.f}, a1 = {0.f, 0.f};
        #pragma unroll
        for (int k = 0; k < NT / 4; ++k) {
            v2f lo = { hq[k].x, hq[k].y };
            v2f hi = { hq[k].z, hq[k].w };
            a0 += E2[2 * k] * lo;
            a1 += E2[2 * k + 1] * hi;
        }
        float d = (a0.x + a1.x) + (a0.y + a1.y);
        q = d * re;
        Clog2 += __log2f(h0);
        if (lane < NT) hs[lane] = q;
    };

    int t = 1;
    while (t + 8 <= L) {
        #pragma unroll
        for (int u = 0; u < 8; ++u) {
            STEP(fb[u]);
            int tp = t + u + 8;
            fb[u] = fbase[(size_t)(tp < SEQ ? tp : 0) * NT];
        }
        t += 8;
    }
    #pragma unroll
    for (int u = 0; u < 8; ++u)
        if (t + u < L) STEP(fb[u]);

    float term = (lane < NT) ? q * Eend : 0.0f;
    #pragma unroll
    for (int m = 32; m >= 1; m >>= 1) term += __shfl_xor(term, m, 64);
    if (lane == 0) out[b] = LN2f * (Clog2 + __log2f(term));
}

extern "C" void kernel_launch(void* const* d_in, const int* in_sizes, int n_in,
                              void* d_out, int out_size, void* d_ws, size_t ws_size,
                              hipStream_t stream) {
    const float* features    = (const float*)d_in[0];
    const float* transitions = (const float*)d_in[1];
    const int*   seqlen      = (const int*)d_in[2];
    float* out = (float*)d_out;

    const size_t need64 = (size_t)TW + (size_t)BATCH * 64 * 4608;   // ~75.6 MB
    const size_t need32 = (size_t)TW + (size_t)BATCH * 32 * 4608;   // ~37.9 MB
    if (ws_size >= need64) {
        crf_setup<<<1, 64, 0, stream>>>(transitions, d_ws);
        crf_phase1<32, 64><<<dim3(BATCH, 16), 256, 0, stream>>>(features, seqlen, d_ws);
        crf_phase2<32, 64><<<BATCH, 64, 0, stream>>>(transitions, seqlen, d_ws, out);
    } else if (ws_size >= need32) {
        crf_setup<<<1, 64, 0, stream>>>(transitions, d_ws);
        crf_phase1<64, 32><<<dim3(BATCH, 8), 256, 0, stream>>>(features, seqlen, d_ws);
        crf_phase2<64, 32><<<BATCH, 64, 0, stream>>>(transitions, seqlen, d_ws, out);
    } else {
        crf_scalar<<<BATCH, 64, 0, stream>>>(features, transitions, seqlen, out);
    }
}

// Round 7
// 158.557 us; speedup vs baseline: 1.0650x; 1.0245x over previous
//
#include <hip/hip_runtime.h>

#define BATCH 256
#define SEQ 2048
#define NT 48
#define START_TAG 46
#define END_TAG 47
#define LN2f  0.6931471805599453f
#define LOG2E 1.4426950408889634f

// ws layout
#define TAF 0          // A-frags of exp(trans) bf16: [9][64] x 8B   (4608 B)
#define TBF 4608       // B-frag exp(trans) f32:      [9][64] x 16B  (9216 B)
#define TSC 16384      // per-chunk log2 scales: [B][NCH] f32        (<=64 KiB)
#define TW  131072     // chunk matrices M^T bf16: [B][NCH][48][48]

typedef float v2f __attribute__((ext_vector_type(2)));
typedef float v4f __attribute__((ext_vector_type(4)));
typedef short s16x4 __attribute__((ext_vector_type(4)));
typedef unsigned int u32;
typedef u32 u32x2 __attribute__((ext_vector_type(2)));
typedef u32 u32x4 __attribute__((ext_vector_type(4)));

__device__ __forceinline__ u32 pkbf(float a, float b) {
    u32 r;
    asm("v_cvt_pk_bf16_f32 %0, %1, %2" : "=v"(r) : "v"(a), "v"(b));
    return r;
}

__device__ __forceinline__ float rfl(float x) {
    return __builtin_bit_cast(float,
        __builtin_amdgcn_readfirstlane(__builtin_bit_cast(int, x)));
}

#if defined(__has_builtin)
#if __has_builtin(__builtin_amdgcn_mfma_f32_16x16x16bf16_1k)
#define MFMA1K 1
#endif
#endif

__device__ __forceinline__ v4f mfma16(s16x4 a, s16x4 b, v4f c) {
#ifdef MFMA1K
    return __builtin_amdgcn_mfma_f32_16x16x16bf16_1k(a, b, c, 0, 0, 0);
#else
    v4f d;
    asm volatile("v_mfma_f32_16x16x16_bf16 %0, %1, %2, %3\n\ts_nop 7\n\ts_nop 7"
                 : "=v"(d) : "v"(a), "v"(b), "v"(c));
    return d;
#endif
}

// sched_group_barrier masks (LLVM SchedGroupMask)
#define SGB(mask, n) __builtin_amdgcn_sched_group_barrier((mask), (n), 0)
#define SG_VALU  0x002
#define SG_MFMA  0x008
#define SG_DSRD  0x100

// ---------------------------------------------------------------------------
// Kernel 0: build exp(trans) fragments once. 1 block x 64.
// A-frag (tile I,K): lane holds E[I*16+(l&15)][K*16+(l>>4)*4+i], i=0..3, bf16.
// B-frag (tile K,J): lane holds E[K*16+(l>>4)*4+i][J*16+(l&15)], f32.
// ---------------------------------------------------------------------------
__global__ void __launch_bounds__(64)
crf_setup(const float* __restrict__ trans, void* ws) {
    __shared__ float el[NT * NT];
    const int lane = threadIdx.x, ln = lane & 15, g = lane >> 4;
    #pragma unroll
    for (int m = 0; m < 36; ++m) {
        int idx = lane + 64 * m;
        el[idx] = __expf(trans[idx]);
    }
    u32x2* AF = (u32x2*)((char*)ws + TAF);
    v4f*   BF = (v4f*)((char*)ws + TBF);
    #pragma unroll
    for (int I = 0; I < 3; ++I)
        #pragma unroll
        for (int K = 0; K < 3; ++K) {
            const v4f ev = *(const v4f*)&el[(I * 16 + ln) * NT + K * 16 + g * 4];
            u32x2 w;
            w.x = pkbf(ev.x, ev.y);
            w.y = pkbf(ev.z, ev.w);
            AF[(I * 3 + K) * 64 + lane] = w;
        }
    #pragma unroll
    for (int K = 0; K < 3; ++K)
        #pragma unroll
        for (int J = 0; J < 3; ++J) {
            v4f v;
            #pragma unroll
            for (int i = 0; i < 4; ++i)
                v[i] = el[(K * 16 + g * 4 + i) * NT + J * 16 + ln];
            BF[(K * 3 + J) * 64 + lane] = v;
        }
}

// ---------------------------------------------------------------------------
// Kernel 1: 4 independent chunk-waves per 256-thread WG (no barriers; each
// wave owns a private LDS slice, wave-ordered DS ops).
// Per (b, chunk c): M_c = prod_{t in chunk} (D_t E) via MFMA chain, M kept in
// B-frag(==C) layout.  Per step: sp = exp2(f*log2e - lg) (lagged P00 rescale
// folded into exponent); 27 MFMA in 3 dependency levels of 9 independent
// MFMAs.  Round-6 lesson: source order alone doesn't control the machine
// scheduler — it re-serialized to K-inner (VGPR_Count 52 == 1 live acc,
// ~17.5 cyc/MFMA latency-exposed).  sched_group_barrier now pins the
// per-level issue order (MFMA x9 / VALU / MFMA x9 / ...), forcing all 9 acc
// tiles live and hiding MFMA latency within each level.
// ---------------------------------------------------------------------------
template<int LCH_, int NCH_>
__global__ void __launch_bounds__(256, 3)
crf_phase1(const float* __restrict__ feat, const int* __restrict__ seqlen,
           void* __restrict__ ws) {
    const int b = blockIdx.x;
    const int wid = threadIdx.x >> 6;
    const int c = blockIdx.y * 4 + wid;
    const int t0 = c * LCH_;
    const int L = seqlen[b];
    int n = L - t0;
    if (n <= 0) return;
    if (n > LCH_) n = LCH_;

    const int lane = threadIdx.x & 63, ln = lane & 15, g = lane >> 4;

    // per-wave emission slice (+16 pad: t+1 prefetch at t=n-1 may touch it)
    __shared__ v4f flv[4][LCH_ * 12 + 16];
    v4f* fl = flv[wid];

    const u32x2* AF = (const u32x2*)((const char*)ws + TAF);
    const v4f*   BF = (const v4f*)((const char*)ws + TBF);

    s16x4 aw[3][3];
    #pragma unroll
    for (int I = 0; I < 3; ++I)
        #pragma unroll
        for (int K = 0; K < 3; ++K)
            aw[I][K] = __builtin_bit_cast(s16x4, AF[(I * 3 + K) * 64 + lane]);

    // stage the whole chunk's emissions (chunk is always within SEQ rows)
    {
        constexpr int NLD = (LCH_ * 12) / 64;
        const v4f* fg = (const v4f*)(feat + ((size_t)b * SEQ + t0) * NT);
        v4f st[NLD];
        #pragma unroll
        for (int m = 0; m < NLD; ++m) st[m] = fg[m * 64 + lane];
        #pragma unroll
        for (int m = 0; m < NLD; ++m) fl[m * 64 + lane] = st[m];
    }

    // init M = D_{t0} E  (row k scaled by exp(emit_{t0}[k]))
    s16x4 mw[3][3];
    {
        v4f emx[3];
        #pragma unroll
        for (int K = 0; K < 3; ++K) {
            v4f f = fl[K * 4 + g];
            #pragma unroll
            for (int i = 0; i < 4; ++i)
                emx[K][i] = __builtin_amdgcn_exp2f(f[i] * LOG2E);
        }
        #pragma unroll
        for (int K = 0; K < 3; ++K)
            #pragma unroll
            for (int J = 0; J < 3; ++J) {
                v4f sc = BF[(K * 3 + J) * 64 + lane] * emx[K];
                mw[K][J] = __builtin_bit_cast(s16x4,
                    (u32x2){pkbf(sc.x, sc.y), pkbf(sc.z, sc.w)});
            }
    }

    // prefetch row 1, pre-scaled by log2e
    v4f ef[3];
    #pragma unroll
    for (int K = 0; K < 3; ++K)
        ef[K] = fl[12 + K * 4 + g] * LOG2E;

    float Lc = 0.f, lg = 0.f;
    const v4f kz = {0.f, 0.f, 0.f, 0.f};

    for (int t = 1; t < n; ++t) {
        // sp = exp2(f*log2e - lg) = exp(f) / gn_prev   (lagged rescale)
        v4f sp[3];
        #pragma unroll
        for (int K = 0; K < 3; ++K) {
            v4f e = ef[K] - lg;
            #pragma unroll
            for (int i = 0; i < 4; ++i) sp[K][i] = __builtin_amdgcn_exp2f(e[i]);
        }
        Lc += lg;

        // prefetch next row's emissions (broadcast ds_read_b128)
        const int tb = (t + 1) * 12 + g;
        v4f fv0 = fl[tb];
        v4f fv1 = fl[tb + 4];
        v4f fv2 = fl[tb + 8];

        // MFMA, K-outer: 9 independent MFMAs per dependency level
        v4f acc[3][3];
        #pragma unroll
        for (int K = 0; K < 3; ++K)
            #pragma unroll
            for (int I = 0; I < 3; ++I)
                #pragma unroll
                for (int J = 0; J < 3; ++J)
                    acc[I][J] = mfma16(aw[I][K], mw[K][J],
                                       K == 0 ? kz : acc[I][J]);

        const float gn = rfl(acc[0][0].x);   // raw P00 -> next-step scale
        #pragma unroll
        for (int K = 0; K < 3; ++K)
            #pragma unroll
            for (int J = 0; J < 3; ++J) {
                v4f sc = acc[K][J] * sp[K];  // v_pk_mul_f32 x2
                mw[K][J] = __builtin_bit_cast(s16x4,
                    (u32x2){pkbf(sc.x, sc.y), pkbf(sc.z, sc.w)});
            }
        lg = __log2f(gn);
        ef[0] = fv0 * LOG2E;
        ef[1] = fv1 * LOG2E;
        ef[2] = fv2 * LOG2E;

        // --- pin the per-step schedule: 3 levels x 9 independent MFMAs,
        // with the transcendental/scale VALU work interleaved in the shadows.
        SGB(SG_DSRD, 3);    // emission prefetch first (latency)
        SGB(SG_MFMA, 9);    // level 0 (the only 9 ready -> level order forced)
        SGB(SG_VALU, 20);   // exp2 / sub / Lc
        SGB(SG_MFMA, 9);    // level 1
        SGB(SG_VALU, 8);
        SGB(SG_MFMA, 9);    // level 2
        SGB(SG_VALU, 60);   // scale + cvt_pk + log2 + ef updates
    }

    // store M^T bf16 (element M[kk][nn] -> byte 2*(nn*48+kk)) + scale
    char* wb = (char*)ws + TW + ((size_t)(b * NCH_ + c)) * 4608;
    #pragma unroll
    for (int K = 0; K < 3; ++K)
        #pragma unroll
        for (int J = 0; J < 3; ++J) {
            u32x2 w = __builtin_bit_cast(u32x2, mw[K][J]);
            *(u32*)(wb + 2 * ((J * 16 + ln) * NT + K * 16 + g * 4))     = w.x;
            *(u32*)(wb + 2 * ((J * 16 + ln) * NT + K * 16 + g * 4 + 2)) = w.y;
        }
    if (lane == 0)
        ((float*)((char*)ws + TSC))[b * NCH_ + c] = Lc;
}

// ---------------------------------------------------------------------------
// Kernel 2: per sample, u^T <- u^T * M_c for c = nb-1..0; lane j owns u[j];
// M^T row j contiguous bf16; next chunk's row double-buffered.
// ---------------------------------------------------------------------------
template<int LCH_, int NCH_>
__global__ void __launch_bounds__(64)
crf_phase2(const float* __restrict__ trans, const int* __restrict__ seqlen,
           const void* __restrict__ ws, float* __restrict__ out) {
    const int b = blockIdx.x;
    const int lane = threadIdx.x;
    const int j = (lane < NT) ? lane : (lane - 16);
    __shared__ v4f hs4[12];
    float* hs = (float*)hs4;

    const int L = seqlen[b];
    const int nb = (L + LCH_ - 1) / LCH_;
    const float* sc = (const float*)((const char*)ws + TSC) + b * NCH_;
    const char* wbase = (const char*)ws + TW + (size_t)b * NCH_ * 4608;

    float q = __expf(trans[END_TAG * NT + j]);   // u0 (exp(MIN)=0 -> col END)
    float D = 0.f;

    u32x4 buf[6];
    {
        const u32x4* wr = (const u32x4*)(wbase + (size_t)(nb - 1) * 4608 + j * 96);
        #pragma unroll
        for (int m = 0; m < 6; ++m) buf[m] = wr[m];
    }

    for (int c = nb - 1; c >= 0; --c) {
        u32x4 cur[6];
        #pragma unroll
        for (int m = 0; m < 6; ++m) cur[m] = buf[m];
        if (c > 0) {
            const u32x4* wr = (const u32x4*)(wbase + (size_t)(c - 1) * 4608 + j * 96);
            #pragma unroll
            for (int m = 0; m < 6; ++m) buf[m] = wr[m];
        }

        if (lane < NT) hs[lane] = q;
        v4f hq[12];
        #pragma unroll
        for (int k = 0; k < 12; ++k) hq[k] = hs4[k];
        const float h0 = hq[0][0];

        v2f a = {0.f, 0.f};
        #pragma unroll
        for (int m = 0; m < 6; ++m) {
            #pragma unroll
            for (int p = 0; p < 4; ++p) {
                const int i = 2 * (4 * m + p);
                u32 w = cur[m][p];
                v2f wp;
                wp.x = __builtin_bit_cast(float, w << 16);
                wp.y = __builtin_bit_cast(float, w & 0xffff0000u);
                v2f up = { hq[i >> 2][i & 3], hq[i >> 2][(i & 3) + 1] };
                a += wp * up;
            }
        }
        const float dot = a.x + a.y;
        q = dot * __builtin_amdgcn_rcpf(h0);
        D += __log2f(h0) + sc[c];
    }
    if (lane < NT) hs[lane] = q;
    if (lane == 0)
        out[b] = LN2f * (D + __log2f(hs[START_TAG]));
}

// ---------------------------------------------------------------------------
// Fallback: proven round-2 scalar kernel (ws too small)
// ---------------------------------------------------------------------------
__global__ void __launch_bounds__(64)
crf_scalar(const float* __restrict__ features, const float* __restrict__ transitions,
           const int* __restrict__ seq_len, float* __restrict__ out) {
    const int b = blockIdx.x;
    const int lane = threadIdx.x;
    const int j = (lane < NT) ? lane : (lane - 16);
    __shared__ v4f hs4[NT / 4];
    float* hs = (float*)hs4;

    v2f E2[NT / 2];
    {
        const v4f* trow = (const v4f*)(transitions + j * NT);
        #pragma unroll
        for (int k = 0; k < NT / 4; ++k) {
            v4f tv = trow[k];
            E2[2 * k].x = __expf(tv.x); E2[2 * k].y = __expf(tv.y);
            E2[2 * k + 1].x = __expf(tv.z); E2[2 * k + 1].y = __expf(tv.w);
        }
    }
    const float Eend = __expf(transitions[END_TAG * NT + j]);
    const int L = seq_len[b];
    const float* fbase = features + ((size_t)b * SEQ) * NT + j;

    float q = E2[START_TAG / 2].x * __expf(fbase[0]);
    float Clog2 = 0.0f;
    if (lane < NT) hs[lane] = q;

    float fb[8];
    #pragma unroll
    for (int u = 0; u < 8; ++u) {
        int tp = 1 + u;
        fb[u] = fbase[(size_t)(tp < SEQ ? tp : 0) * NT];
    }

    auto STEP = [&](float femit) {
        v4f hq[NT / 4];
        #pragma unroll
        for (int k = 0; k < NT / 4; ++k) hq[k] = hs4[k];
        float h0 = hq[0].x;
        float r = __builtin_amdgcn_rcpf(h0);
        float e = __expf(femit);
        float re = r * e;
        v2f a0 = {0.f, 0.f}, a1 = {0.f, 0.f};
        #pragma unroll
        for (int k = 0; k < NT / 4; ++k) {
            v2f lo = { hq[k].x, hq[k].y };
            v2f hi = { hq[k].z, hq[k].w };
            a0 += E2[2 * k] * lo;
            a1 += E2[2 * k + 1] * hi;
        }
        float d = (a0.x + a1.x) + (a0.y + a1.y);
        q = d * re;
        Clog2 += __log2f(h0);
        if (lane < NT) hs[lane] = q;
    };

    int t = 1;
    while (t + 8 <= L) {
        #pragma unroll
        for (int u = 0; u < 8; ++u) {
            STEP(fb[u]);
            int tp = t + u + 8;
            fb[u] = fbase[(size_t)(tp < SEQ ? tp : 0) * NT];
        }
        t += 8;
    }
    #pragma unroll
    for (int u = 0; u < 8; ++u)
        if (t + u < L) STEP(fb[u]);

    float term = (lane < NT) ? q * Eend : 0.0f;
    #pragma unroll
    for (int m = 32; m >= 1; m >>= 1) term += __shfl_xor(term, m, 64);
    if (lane == 0) out[b] = LN2f * (Clog2 + __log2f(term));
}

extern "C" void kernel_launch(void* const* d_in, const int* in_sizes, int n_in,
                              void* d_out, int out_size, void* d_ws, size_t ws_size,
                              hipStream_t stream) {
    const float* features    = (const float*)d_in[0];
    const float* transitions = (const float*)d_in[1];
    const int*   seqlen      = (const int*)d_in[2];
    float* out = (float*)d_out;

    const size_t need64 = (size_t)TW + (size_t)BATCH * 64 * 4608;   // ~75.6 MB
    const size_t need32 = (size_t)TW + (size_t)BATCH * 32 * 4608;   // ~37.9 MB
    if (ws_size >= need64) {
        crf_setup<<<1, 64, 0, stream>>>(transitions, d_ws);
        crf_phase1<32, 64><<<dim3(BATCH, 16), 256, 0, stream>>>(features, seqlen, d_ws);
        crf_phase2<32, 64><<<BATCH, 64, 0, stream>>>(transitions, seqlen, d_ws, out);
    } else if (ws_size >= need32) {
        crf_setup<<<1, 64, 0, stream>>>(transitions, d_ws);
        crf_phase1<64, 32><<<dim3(BATCH, 8), 256, 0, stream>>>(features, seqlen, d_ws);
        crf_phase2<64, 32><<<BATCH, 64, 0, stream>>>(transitions, seqlen, d_ws, out);
    } else {
        crf_scalar<<<BATCH, 64, 0, stream>>>(features, transitions, seqlen, out);
    }
}